// Round 1
// baseline (831.970 us; speedup 1.0000x reference)
//
#include <hip/hip_runtime.h>

#define NODES 50000

// ---------------- degree / CSR build ----------------

__global__ void k_count(const int* __restrict__ dst, int E, int* __restrict__ degcnt) {
    int e = blockIdx.x * blockDim.x + threadIdx.x;
    if (e < E) atomicAdd(&degcnt[dst[e]], 1);
}

__global__ void k_dinv(const int* __restrict__ degcnt, float* __restrict__ dinv, int n) {
    int i = blockIdx.x * blockDim.x + threadIdx.x;
    if (i < n) dinv[i] = rsqrtf(1.0f + (float)degcnt[i]);
}

// single-block exclusive scan over n entries; also writes rowstart[n] = total
__global__ void k_scan(const int* __restrict__ cnt, int* __restrict__ rowstart, int n) {
    __shared__ int s[1024];
    int t = threadIdx.x;
    int chunk = (n + 1023) >> 10;
    int lo = t * chunk, hi = min(lo + chunk, n);
    int sum = 0;
    for (int i = lo; i < hi; ++i) sum += cnt[i];
    s[t] = sum;
    __syncthreads();
    for (int off = 1; off < 1024; off <<= 1) {
        int v = (t >= off) ? s[t - off] : 0;
        __syncthreads();
        s[t] += v;
        __syncthreads();
    }
    int run = (t == 0) ? 0 : s[t - 1];
    for (int i = lo; i < hi; ++i) { rowstart[i] = run; run += cnt[i]; }
    if (t == 1023) rowstart[n] = s[1023];
}

__global__ void k_scatter(const int* __restrict__ src, const int* __restrict__ dst, int E,
                          const int* __restrict__ rowstart, int* __restrict__ cursor,
                          int* __restrict__ ssrc) {
    int e = blockIdx.x * blockDim.x + threadIdx.x;
    if (e < E) {
        int d = dst[e];
        int p = atomicAdd(&cursor[d], 1);
        ssrc[rowstart[d] + p] = src[e];
    }
}

// ---------------- f32 tiled GEMM: C[M,N] = A[M,K] @ B[K,N] ----------------
// BM=BN=64, BK=16, 256 threads, 4x4 per thread. Requires N%64==0, K%16==0.
__global__ __launch_bounds__(256) void k_gemm(const float* __restrict__ A,
                                              const float* __restrict__ B,
                                              float* __restrict__ C,
                                              int M, int N, int K) {
    __shared__ float As[16][64];  // [k][m]
    __shared__ float Bs[16][64];  // [k][n]
    int t = threadIdx.x;
    int tx = t & 15, ty = t >> 4;
    int bm = blockIdx.x * 64, bn = blockIdx.y * 64;
    float acc[4][4] = {};

    for (int k0 = 0; k0 < K; k0 += 16) {
        // A tile: thread t loads one float4: m = t>>2 (0..63), kq = t&3 (0..3)
        {
            int m = t >> 2, kq = t & 3;
            float4 av = make_float4(0.f, 0.f, 0.f, 0.f);
            int row = bm + m;
            if (row < M) av = *(const float4*)(A + (size_t)row * K + k0 + kq * 4);
            As[kq * 4 + 0][m] = av.x;
            As[kq * 4 + 1][m] = av.y;
            As[kq * 4 + 2][m] = av.z;
            As[kq * 4 + 3][m] = av.w;
            // B tile: kb = t>>4 (0..15), q = t&15
            int kb = t >> 4, q = t & 15;
            float4 bv = *(const float4*)(B + (size_t)(k0 + kb) * N + bn + q * 4);
            *(float4*)&Bs[kb][q * 4] = bv;
        }
        __syncthreads();
#pragma unroll
        for (int k = 0; k < 16; ++k) {
            float4 a = *(const float4*)&As[k][ty * 4];
            float4 b = *(const float4*)&Bs[k][tx * 4];
            float av[4] = {a.x, a.y, a.z, a.w};
            float bv[4] = {b.x, b.y, b.z, b.w};
#pragma unroll
            for (int i = 0; i < 4; ++i)
#pragma unroll
                for (int j = 0; j < 4; ++j)
                    acc[i][j] = fmaf(av[i], bv[j], acc[i][j]);
        }
        __syncthreads();
    }
#pragma unroll
    for (int i = 0; i < 4; ++i) {
        int row = bm + ty * 4 + i;
        if (row < M)
            *(float4*)(C + (size_t)row * N + bn + tx * 4) =
                make_float4(acc[i][0], acc[i][1], acc[i][2], acc[i][3]);
    }
}

// ---------------- layer-1 aggregation + bias + relu ----------------
// one wave per node; lane l owns dims 4l..4l+3 (256 dims)
__global__ __launch_bounds__(256) void k_agg1(const float* __restrict__ h,
                                              const int* __restrict__ rowstart,
                                              const int* __restrict__ ssrc,
                                              const float* __restrict__ dinv,
                                              const float* __restrict__ b1,
                                              float* __restrict__ out) {
    int wave = threadIdx.x >> 6;
    int lane = threadIdx.x & 63;
    int n = blockIdx.x * 4 + wave;
    if (n >= NODES) return;
    float4 acc = make_float4(0.f, 0.f, 0.f, 0.f);
    int e0 = rowstart[n], e1 = rowstart[n + 1];
    for (int e = e0; e < e1; ++e) {
        int s = ssrc[e];
        float w = dinv[s];
        float4 v = *(const float4*)(h + (size_t)s * 256 + lane * 4);
        acc.x = fmaf(w, v.x, acc.x);
        acc.y = fmaf(w, v.y, acc.y);
        acc.z = fmaf(w, v.z, acc.z);
        acc.w = fmaf(w, v.w, acc.w);
    }
    float dn = dinv[n];
    float s2 = dn * dn;
    float4 hv = *(const float4*)(h + (size_t)n * 256 + lane * 4);
    float4 bb = *(const float4*)(b1 + lane * 4);
    float4 r;
    r.x = fmaxf(fmaf(acc.x, dn, fmaf(hv.x, s2, bb.x)), 0.f);
    r.y = fmaxf(fmaf(acc.y, dn, fmaf(hv.y, s2, bb.y)), 0.f);
    r.z = fmaxf(fmaf(acc.z, dn, fmaf(hv.z, s2, bb.z)), 0.f);
    r.w = fmaxf(fmaf(acc.w, dn, fmaf(hv.w, s2, bb.w)), 0.f);
    *(float4*)(out + (size_t)n * 256 + lane * 4) = r;
}

// ---------------- layer-2 aggregation + bias + log_softmax ----------------
// one wave per node; lane l owns dim l (64 dims)
__global__ __launch_bounds__(256) void k_agg2(const float* __restrict__ h,
                                              const int* __restrict__ rowstart,
                                              const int* __restrict__ ssrc,
                                              const float* __restrict__ dinv,
                                              const float* __restrict__ b2,
                                              float* __restrict__ out) {
    int wave = threadIdx.x >> 6;
    int lane = threadIdx.x & 63;
    int n = blockIdx.x * 4 + wave;
    if (n >= NODES) return;
    float acc = 0.f;
    int e0 = rowstart[n], e1 = rowstart[n + 1];
    for (int e = e0; e < e1; ++e) {
        int s = ssrc[e];
        acc = fmaf(dinv[s], h[(size_t)s * 64 + lane], acc);
    }
    float dn = dinv[n];
    float r = fmaf(acc, dn, fmaf(h[(size_t)n * 64 + lane], dn * dn, b2[lane]));
    // log_softmax over the 64 lanes
    float m = r;
#pragma unroll
    for (int off = 32; off; off >>= 1) m = fmaxf(m, __shfl_xor(m, off));
    float ex = __expf(r - m);
    float ssum = ex;
#pragma unroll
    for (int off = 32; off; off >>= 1) ssum += __shfl_xor(ssum, off);
    out[(size_t)n * 64 + lane] = r - m - __logf(ssum);
}

// ---------------- launch ----------------

extern "C" void kernel_launch(void* const* d_in, const int* in_sizes, int n_in,
                              void* d_out, int out_size, void* d_ws, size_t ws_size,
                              hipStream_t stream) {
    const float* x  = (const float*)d_in[0];
    const float* W1 = (const float*)d_in[1];
    const float* b1 = (const float*)d_in[2];
    const float* W2 = (const float*)d_in[3];
    const float* b2 = (const float*)d_in[4];
    const int*   ei = (const int*)d_in[5];
    int E = in_sizes[5] / 2;
    const int* src = ei;
    const int* dst = ei + E;
    float* out = (float*)d_out;

    char* wsp = (char*)d_ws;
    auto alloc = [&](size_t bytes) {
        char* p = wsp;
        wsp += (bytes + 255) & ~(size_t)255;
        return p;
    };
    int*   degcnt   = (int*)alloc((size_t)NODES * 4);
    float* dinv     = (float*)alloc((size_t)NODES * 4);
    int*   rowstart = (int*)alloc((size_t)(NODES + 1) * 4);
    int*   cursor   = (int*)alloc((size_t)NODES * 4);
    int*   ssrc     = (int*)alloc((size_t)E * 4);
    float* h1       = (float*)alloc((size_t)NODES * 256 * 4);
    float* h1a      = (float*)alloc((size_t)NODES * 256 * 4);
    float* h2       = h1;  // h1 is dead after k_agg1; reuse for layer-2 GEMM out

    hipMemsetAsync(degcnt, 0, (size_t)NODES * 4, stream);
    hipMemsetAsync(cursor, 0, (size_t)NODES * 4, stream);

    k_count<<<(E + 255) / 256, 256, 0, stream>>>(dst, E, degcnt);
    k_dinv<<<(NODES + 255) / 256, 256, 0, stream>>>(degcnt, dinv, NODES);
    k_scan<<<1, 1024, 0, stream>>>(degcnt, rowstart, NODES);
    k_scatter<<<(E + 255) / 256, 256, 0, stream>>>(src, dst, E, rowstart, cursor, ssrc);

    // layer 1: h1 = x @ W1   [50000,512]@[512,256]
    k_gemm<<<dim3((NODES + 63) / 64, 256 / 64), 256, 0, stream>>>(x, W1, h1, NODES, 256, 512);
    k_agg1<<<(NODES + 3) / 4, 256, 0, stream>>>(h1, rowstart, ssrc, dinv, b1, h1a);

    // layer 2: h2 = h1a @ W2   [50000,256]@[256,64]
    k_gemm<<<dim3((NODES + 63) / 64, 64 / 64), 256, 0, stream>>>(h1a, W2, h2, NODES, 64, 256);
    k_agg2<<<(NODES + 3) / 4, 256, 0, stream>>>(h2, rowstart, ssrc, dinv, b2, out);
}

// Round 2
// 642.698 us; speedup vs baseline: 1.2945x; 1.2945x over previous
//
#include <hip/hip_runtime.h>

#define NODES 50000

typedef __attribute__((ext_vector_type(8))) short short8;
typedef __attribute__((ext_vector_type(4))) float f32x4;

__device__ __forceinline__ ushort f2bf(float f) {
    uint u = __float_as_uint(f);
    uint r = (u + 0x7fffu + ((u >> 16) & 1u)) >> 16;
    return (ushort)r;
}
__device__ __forceinline__ float bf2f(ushort u) {
    return __uint_as_float(((uint)u) << 16);
}

// ---------------- degree / CSR build ----------------

__global__ void k_count(const int* __restrict__ dst, int E, int* __restrict__ degcnt) {
    int e = blockIdx.x * blockDim.x + threadIdx.x;
    if (e < E) atomicAdd(&degcnt[dst[e]], 1);
}

__global__ void k_dinv(const int* __restrict__ degcnt, float* __restrict__ dinv, int n) {
    int i = blockIdx.x * blockDim.x + threadIdx.x;
    if (i < n) dinv[i] = rsqrtf(1.0f + (float)degcnt[i]);
}

// single-block exclusive scan over n entries; also writes rowstart[n] = total
__global__ void k_scan(const int* __restrict__ cnt, int* __restrict__ rowstart, int n) {
    __shared__ int s[1024];
    int t = threadIdx.x;
    int chunk = (n + 1023) >> 10;
    int lo = t * chunk, hi = min(lo + chunk, n);
    int sum = 0;
    for (int i = lo; i < hi; ++i) sum += cnt[i];
    s[t] = sum;
    __syncthreads();
    for (int off = 1; off < 1024; off <<= 1) {
        int v = (t >= off) ? s[t - off] : 0;
        __syncthreads();
        s[t] += v;
        __syncthreads();
    }
    int run = (t == 0) ? 0 : s[t - 1];
    for (int i = lo; i < hi; ++i) { rowstart[i] = run; run += cnt[i]; }
    if (t == 1023) rowstart[n] = s[1023];
}

__global__ void k_scatter(const int* __restrict__ src, const int* __restrict__ dst, int E,
                          const int* __restrict__ rowstart, int* __restrict__ cursor,
                          int* __restrict__ ssrc) {
    int e = blockIdx.x * blockDim.x + threadIdx.x;
    if (e < E) {
        int d = dst[e];
        int p = atomicAdd(&cursor[d], 1);
        ssrc[rowstart[d] + p] = src[e];
    }
}

// ---------------- casts ----------------

// f32 -> bf16, 8 elems/thread, n % 8 == 0
__global__ void k_cast8(const float* __restrict__ in, ushort* __restrict__ out, int n) {
    int base = (blockIdx.x * blockDim.x + threadIdx.x) * 8;
    if (base >= n) return;
    float4 a = *(const float4*)(in + base);
    float4 b = *(const float4*)(in + base + 4);
    ushort r[8] = {f2bf(a.x), f2bf(a.y), f2bf(a.z), f2bf(a.w),
                   f2bf(b.x), f2bf(b.y), f2bf(b.z), f2bf(b.w)};
    *(short8*)(out + base) = *(short8*)r;
}

// in [R][C] f32 -> out [C][R] bf16 (transpose cast; tiny matrices only)
__global__ void k_castT(const float* __restrict__ in, ushort* __restrict__ out, int R, int C) {
    int i = blockIdx.x * blockDim.x + threadIdx.x;
    if (i >= R * C) return;
    int r = i / C, c = i % C;
    out[(size_t)c * R + r] = f2bf(in[i]);
}

// ---------------- bf16 MFMA GEMM: C[M,N] = A[M,K] @ Bt[N,K]^T ----------------
// BM=128 fixed; 256 threads = 4 waves in WM x WN grid (WM*WN=4).
// A row-major bf16 [M][K]; Bt row-major bf16 [N][K]; K%32==0, N%BN==0.
template <int BN, int WN, bool OUTBF>
__global__ __launch_bounds__(256) void k_gemm_bf16(const ushort* __restrict__ A,
                                                   const ushort* __restrict__ Bt,
                                                   float* __restrict__ C,
                                                   ushort* __restrict__ Cb,
                                                   int M, int N, int K) {
    constexpr int WM = 4 / WN;
    constexpr int WTM = 128 / WM;   // wave tile rows
    constexpr int WTN = BN / WN;    // wave tile cols
    constexpr int MT = WTM / 16;
    constexpr int NT = WTN / 16;
    constexpr int SA = 48;          // padded LDS row stride (elems, 96B: 16B-aligned, 4-way banks)
    __shared__ ushort As[128 * SA];
    __shared__ ushort Bs[BN * SA];

    int t = threadIdx.x;
    int w = t >> 6, l = t & 63;
    int wm = w % WM, wn = w / WM;
    int bm = blockIdx.x * 128, bn = blockIdx.y * BN;
    int lr = l & 15, lk = (l >> 4) * 8;

    f32x4 acc[MT][NT] = {};
    const int ACH = 128 * 4;
    const int BCH = BN * 4;

    for (int k0 = 0; k0 < K; k0 += 32) {
        for (int c = t; c < ACH + BCH; c += 256) {
            if (c < ACH) {
                int row = c >> 2, seg = c & 3;
                int gr = bm + row;
                int4 v = make_int4(0, 0, 0, 0);
                if (gr < M) v = *(const int4*)(A + (size_t)gr * K + k0 + seg * 8);
                *(int4*)(&As[row * SA + seg * 8]) = v;
            } else {
                int cc = c - ACH;
                int row = cc >> 2, seg = cc & 3;
                int4 v = *(const int4*)(Bt + (size_t)(bn + row) * K + k0 + seg * 8);
                *(int4*)(&Bs[row * SA + seg * 8]) = v;
            }
        }
        __syncthreads();
        short8 af[MT], bfr[NT];
#pragma unroll
        for (int mt = 0; mt < MT; ++mt)
            af[mt] = *(const short8*)(&As[(wm * WTM + mt * 16 + lr) * SA + lk]);
#pragma unroll
        for (int nt = 0; nt < NT; ++nt)
            bfr[nt] = *(const short8*)(&Bs[(wn * WTN + nt * 16 + lr) * SA + lk]);
#pragma unroll
        for (int mt = 0; mt < MT; ++mt)
#pragma unroll
            for (int nt = 0; nt < NT; ++nt)
                acc[mt][nt] = __builtin_amdgcn_mfma_f32_16x16x32_bf16(af[mt], bfr[nt], acc[mt][nt], 0, 0, 0);
        __syncthreads();
    }

#pragma unroll
    for (int mt = 0; mt < MT; ++mt)
#pragma unroll
        for (int nt = 0; nt < NT; ++nt)
#pragma unroll
            for (int i = 0; i < 4; ++i) {
                int row = bm + wm * WTM + mt * 16 + (l >> 4) * 4 + i;
                int col = bn + wn * WTN + nt * 16 + lr;
                if (row < M) {
                    float v = acc[mt][nt][i];
                    if (OUTBF) Cb[(size_t)row * N + col] = f2bf(v);
                    else       C[(size_t)row * N + col] = v;
                }
            }
}

// ---------------- layer-1 aggregation + bias + relu (bf16 in / bf16 out) ----------------
// one wave per node; lane l owns dims 4l..4l+3 (256 dims)
__global__ __launch_bounds__(256) void k_agg1(const ushort* __restrict__ h,
                                              const int* __restrict__ rowstart,
                                              const int* __restrict__ ssrc,
                                              const float* __restrict__ dinv,
                                              const float* __restrict__ b1,
                                              ushort* __restrict__ out) {
    int wave = threadIdx.x >> 6;
    int lane = threadIdx.x & 63;
    int n = blockIdx.x * 4 + wave;
    if (n >= NODES) return;
    float4 acc = make_float4(0.f, 0.f, 0.f, 0.f);
    int e0 = rowstart[n], e1 = rowstart[n + 1];
    for (int e = e0; e < e1; ++e) {
        int s = ssrc[e];
        float w = dinv[s];
        ushort4 v = *(const ushort4*)(h + (size_t)s * 256 + lane * 4);
        acc.x = fmaf(w, bf2f(v.x), acc.x);
        acc.y = fmaf(w, bf2f(v.y), acc.y);
        acc.z = fmaf(w, bf2f(v.z), acc.z);
        acc.w = fmaf(w, bf2f(v.w), acc.w);
    }
    float dn = dinv[n];
    float s2 = dn * dn;
    ushort4 hv = *(const ushort4*)(h + (size_t)n * 256 + lane * 4);
    float4 bb = *(const float4*)(b1 + lane * 4);
    ushort4 r;
    r.x = f2bf(fmaxf(fmaf(acc.x, dn, fmaf(bf2f(hv.x), s2, bb.x)), 0.f));
    r.y = f2bf(fmaxf(fmaf(acc.y, dn, fmaf(bf2f(hv.y), s2, bb.y)), 0.f));
    r.z = f2bf(fmaxf(fmaf(acc.z, dn, fmaf(bf2f(hv.z), s2, bb.z)), 0.f));
    r.w = f2bf(fmaxf(fmaf(acc.w, dn, fmaf(bf2f(hv.w), s2, bb.w)), 0.f));
    *(ushort4*)(out + (size_t)n * 256 + lane * 4) = r;
}

// ---------------- layer-2 aggregation + bias + log_softmax (f32 h2) ----------------
// one wave per node; lane l owns dim l (64 dims)
__global__ __launch_bounds__(256) void k_agg2(const float* __restrict__ h,
                                              const int* __restrict__ rowstart,
                                              const int* __restrict__ ssrc,
                                              const float* __restrict__ dinv,
                                              const float* __restrict__ b2,
                                              float* __restrict__ out) {
    int wave = threadIdx.x >> 6;
    int lane = threadIdx.x & 63;
    int n = blockIdx.x * 4 + wave;
    if (n >= NODES) return;
    float acc = 0.f;
    int e0 = rowstart[n], e1 = rowstart[n + 1];
    for (int e = e0; e < e1; ++e) {
        int s = ssrc[e];
        acc = fmaf(dinv[s], h[(size_t)s * 64 + lane], acc);
    }
    float dn = dinv[n];
    float r = fmaf(acc, dn, fmaf(h[(size_t)n * 64 + lane], dn * dn, b2[lane]));
    float m = r;
#pragma unroll
    for (int off = 32; off; off >>= 1) m = fmaxf(m, __shfl_xor(m, off));
    float ex = __expf(r - m);
    float ssum = ex;
#pragma unroll
    for (int off = 32; off; off >>= 1) ssum += __shfl_xor(ssum, off);
    out[(size_t)n * 64 + lane] = r - m - __logf(ssum);
}

// ---------------- launch ----------------

extern "C" void kernel_launch(void* const* d_in, const int* in_sizes, int n_in,
                              void* d_out, int out_size, void* d_ws, size_t ws_size,
                              hipStream_t stream) {
    const float* x  = (const float*)d_in[0];
    const float* W1 = (const float*)d_in[1];
    const float* b1 = (const float*)d_in[2];
    const float* W2 = (const float*)d_in[3];
    const float* b2 = (const float*)d_in[4];
    const int*   ei = (const int*)d_in[5];
    int E = in_sizes[5] / 2;
    const int* src = ei;
    const int* dst = ei + E;
    float* out = (float*)d_out;

    char* wsp = (char*)d_ws;
    auto alloc = [&](size_t bytes) {
        char* p = wsp;
        wsp += (bytes + 255) & ~(size_t)255;
        return p;
    };
    int*    degcnt   = (int*)alloc((size_t)NODES * 4);
    float*  dinv     = (float*)alloc((size_t)NODES * 4);
    int*    rowstart = (int*)alloc((size_t)(NODES + 1) * 4);
    int*    cursor   = (int*)alloc((size_t)NODES * 4);
    int*    ssrc     = (int*)alloc((size_t)E * 4);
    ushort* xb       = (ushort*)alloc((size_t)NODES * 512 * 2);   // bf16 x
    ushort* w1t      = (ushort*)alloc((size_t)256 * 512 * 2);     // W1^T bf16 [256][512]
    ushort* h1b      = (ushort*)alloc((size_t)NODES * 256 * 2);   // bf16 h1
    ushort* h1ab     = (ushort*)alloc((size_t)NODES * 256 * 2);   // bf16 relu(agg1)
    ushort* w2t      = (ushort*)alloc((size_t)64 * 256 * 2);      // W2^T bf16 [64][256]
    float*  h2       = (float*)xb;  // xb dead after gemm1; reuse (12.8 MB < 51.2 MB)

    hipMemsetAsync(degcnt, 0, (size_t)NODES * 4, stream);
    hipMemsetAsync(cursor, 0, (size_t)NODES * 4, stream);

    k_count<<<(E + 255) / 256, 256, 0, stream>>>(dst, E, degcnt);
    k_dinv<<<(NODES + 255) / 256, 256, 0, stream>>>(degcnt, dinv, NODES);
    k_scan<<<1, 1024, 0, stream>>>(degcnt, rowstart, NODES);
    k_scatter<<<(E + 255) / 256, 256, 0, stream>>>(src, dst, E, rowstart, cursor, ssrc);

    // casts
    int nx = NODES * 512;
    k_cast8<<<(nx / 8 + 255) / 256, 256, 0, stream>>>(x, xb, nx);
    k_castT<<<(512 * 256 + 255) / 256, 256, 0, stream>>>(W1, w1t, 512, 256);
    k_castT<<<(256 * 64 + 255) / 256, 256, 0, stream>>>(W2, w2t, 256, 64);

    // layer 1: h1 = x @ W1  [50000,512]x[512,256] -> bf16
    k_gemm_bf16<128, 2, true><<<dim3((NODES + 127) / 128, 256 / 128), 256, 0, stream>>>(
        xb, w1t, nullptr, h1b, NODES, 256, 512);
    k_agg1<<<(NODES + 3) / 4, 256, 0, stream>>>(h1b, rowstart, ssrc, dinv, b1, h1ab);

    // layer 2: h2 = h1a @ W2  [50000,256]x[256,64] -> f32
    k_gemm_bf16<64, 1, false><<<dim3((NODES + 127) / 128, 1), 256, 0, stream>>>(
        h1ab, w2t, h2, nullptr, NODES, 64, 256);
    k_agg2<<<(NODES + 3) / 4, 256, 0, stream>>>(h2, rowstart, ssrc, dinv, b2, out);
}

// Round 3
// 534.843 us; speedup vs baseline: 1.5555x; 1.2017x over previous
//
#include <hip/hip_runtime.h>

#define NODES 50000

typedef __attribute__((ext_vector_type(8))) short short8;
typedef __attribute__((ext_vector_type(4))) float f32x4;

__device__ __forceinline__ ushort f2bf(float f) {
    uint u = __float_as_uint(f);
    uint r = (u + 0x7fffu + ((u >> 16) & 1u)) >> 16;
    return (ushort)r;
}
__device__ __forceinline__ float bf2f(ushort u) {
    return __uint_as_float(((uint)u) << 16);
}

// ---------------- degree / CSR build ----------------

__global__ void k_count(const int* __restrict__ dst, int E, int* __restrict__ degcnt) {
    int e = blockIdx.x * blockDim.x + threadIdx.x;
    if (e < E) atomicAdd(&degcnt[dst[e]], 1);
}

// single-block exclusive scan; also writes rowstart[n]=total and dinv[]
__global__ void k_scan(const int* __restrict__ cnt, int* __restrict__ rowstart,
                       float* __restrict__ dinv, int n) {
    __shared__ int s[1024];
    int t = threadIdx.x;
    int chunk = (n + 1023) >> 10;
    int lo = t * chunk, hi = min(lo + chunk, n);
    int sum = 0;
    for (int i = lo; i < hi; ++i) sum += cnt[i];
    s[t] = sum;
    __syncthreads();
    for (int off = 1; off < 1024; off <<= 1) {
        int v = (t >= off) ? s[t - off] : 0;
        __syncthreads();
        s[t] += v;
        __syncthreads();
    }
    int run = (t == 0) ? 0 : s[t - 1];
    for (int i = lo; i < hi; ++i) {
        rowstart[i] = run;
        run += cnt[i];
        dinv[i] = rsqrtf(1.0f + (float)cnt[i]);
    }
    if (t == 1023) rowstart[n] = s[1023];
}

// edge record: {src, bits(dinv[src])} -> one broadcast 8B load per edge later
__global__ void k_scatter(const int* __restrict__ src, const int* __restrict__ dst, int E,
                          const int* __restrict__ rowstart, int* __restrict__ cursor,
                          const float* __restrict__ dinv, int2* __restrict__ erec) {
    int e = blockIdx.x * blockDim.x + threadIdx.x;
    if (e < E) {
        int d = dst[e];
        int s = src[e];
        int p = atomicAdd(&cursor[d], 1);
        erec[rowstart[d] + p] = make_int2(s, __float_as_int(dinv[s]));
    }
}

// ---------------- casts ----------------

// in [R][C] f32 -> out [C][R] bf16 (transpose cast; weights only)
__global__ void k_castT(const float* __restrict__ in, ushort* __restrict__ out, int R, int C) {
    int i = blockIdx.x * blockDim.x + threadIdx.x;
    if (i >= R * C) return;
    int r = i / C, c = i % C;
    out[(size_t)c * R + r] = f2bf(in[i]);
}

// ---------------- bf16 MFMA GEMM: C[M,N] = A[M,K] @ Bt[N,K]^T ----------------
// BM=128; 256 threads = 4 waves. A either f32 (cast during staging) or bf16.
template <int BN, int WN, bool A_F32, bool OUTBF>
__global__ __launch_bounds__(256) void k_gemm_bf16(const float* __restrict__ Af,
                                                   const ushort* __restrict__ Ab,
                                                   const ushort* __restrict__ Bt,
                                                   float* __restrict__ C,
                                                   ushort* __restrict__ Cb,
                                                   int M, int N, int K) {
    constexpr int WM = 4 / WN;
    constexpr int WTM = 128 / WM;
    constexpr int WTN = BN / WN;
    constexpr int MT = WTM / 16;
    constexpr int NT = WTN / 16;
    constexpr int SA = 48;  // padded LDS row stride (elems)
    __shared__ ushort As[128 * SA];
    __shared__ ushort Bs[BN * SA];

    int t = threadIdx.x;
    int w = t >> 6, l = t & 63;
    int wm = w % WM, wn = w / WM;
    int bm = blockIdx.x * 128, bn = blockIdx.y * BN;
    int lr = l & 15, lk = (l >> 4) * 8;

    f32x4 acc[MT][NT] = {};
    const int ACH = 128 * 4;
    const int BCH = BN * 4;

    for (int k0 = 0; k0 < K; k0 += 32) {
        for (int c = t; c < ACH + BCH; c += 256) {
            if (c < ACH) {
                int row = c >> 2, seg = c & 3;
                int gr = bm + row;
                if (A_F32) {
                    ushort r[8] = {0, 0, 0, 0, 0, 0, 0, 0};
                    if (gr < M) {
                        float4 a = *(const float4*)(Af + (size_t)gr * K + k0 + seg * 8);
                        float4 b = *(const float4*)(Af + (size_t)gr * K + k0 + seg * 8 + 4);
                        r[0] = f2bf(a.x); r[1] = f2bf(a.y); r[2] = f2bf(a.z); r[3] = f2bf(a.w);
                        r[4] = f2bf(b.x); r[5] = f2bf(b.y); r[6] = f2bf(b.z); r[7] = f2bf(b.w);
                    }
                    *(int4*)(&As[row * SA + seg * 8]) = *(int4*)r;
                } else {
                    int4 v = make_int4(0, 0, 0, 0);
                    if (gr < M) v = *(const int4*)(Ab + (size_t)gr * K + k0 + seg * 8);
                    *(int4*)(&As[row * SA + seg * 8]) = v;
                }
            } else {
                int cc = c - ACH;
                int row = cc >> 2, seg = cc & 3;
                int4 v = *(const int4*)(Bt + (size_t)(bn + row) * K + k0 + seg * 8);
                *(int4*)(&Bs[row * SA + seg * 8]) = v;
            }
        }
        __syncthreads();
        short8 af[MT], bfr[NT];
#pragma unroll
        for (int mt = 0; mt < MT; ++mt)
            af[mt] = *(const short8*)(&As[(wm * WTM + mt * 16 + lr) * SA + lk]);
#pragma unroll
        for (int nt = 0; nt < NT; ++nt)
            bfr[nt] = *(const short8*)(&Bs[(wn * WTN + nt * 16 + lr) * SA + lk]);
#pragma unroll
        for (int mt = 0; mt < MT; ++mt)
#pragma unroll
            for (int nt = 0; nt < NT; ++nt)
                acc[mt][nt] = __builtin_amdgcn_mfma_f32_16x16x32_bf16(af[mt], bfr[nt], acc[mt][nt], 0, 0, 0);
        __syncthreads();
    }

#pragma unroll
    for (int mt = 0; mt < MT; ++mt)
#pragma unroll
        for (int nt = 0; nt < NT; ++nt)
#pragma unroll
            for (int i = 0; i < 4; ++i) {
                int row = bm + wm * WTM + mt * 16 + (l >> 4) * 4 + i;
                int col = bn + wn * WTN + nt * 16 + lr;
                if (row < M) {
                    float v = acc[mt][nt][i];
                    if (OUTBF) Cb[(size_t)row * N + col] = f2bf(v);
                    else       C[(size_t)row * N + col] = v;
                }
            }
}

// ---------------- layer-1 aggregation + bias + relu (bf16 in / bf16 out) ----------------
// one wave per node; lane l owns dims 4l..4l+3; edge loop unrolled x4 for MLP
__global__ __launch_bounds__(256) void k_agg1(const ushort* __restrict__ h,
                                              const int* __restrict__ rowstart,
                                              const int2* __restrict__ er,
                                              const float* __restrict__ dinv,
                                              const float* __restrict__ b1,
                                              ushort* __restrict__ out) {
    int wave = threadIdx.x >> 6;
    int lane = threadIdx.x & 63;
    int n = blockIdx.x * 4 + wave;
    if (n >= NODES) return;
    float4 acc = make_float4(0.f, 0.f, 0.f, 0.f);
    int e0 = rowstart[n], e1 = rowstart[n + 1];
    int e = e0;
#define A1_STEP(q, v)                                             \
    {                                                             \
        float w = __int_as_float((q).y);                          \
        acc.x = fmaf(w, bf2f((v).x), acc.x);                      \
        acc.y = fmaf(w, bf2f((v).y), acc.y);                      \
        acc.z = fmaf(w, bf2f((v).z), acc.z);                      \
        acc.w = fmaf(w, bf2f((v).w), acc.w);                      \
    }
    for (; e + 4 <= e1; e += 4) {
        int2 q0 = er[e], q1 = er[e + 1], q2 = er[e + 2], q3 = er[e + 3];
        ushort4 v0 = *(const ushort4*)(h + (size_t)q0.x * 256 + lane * 4);
        ushort4 v1 = *(const ushort4*)(h + (size_t)q1.x * 256 + lane * 4);
        ushort4 v2 = *(const ushort4*)(h + (size_t)q2.x * 256 + lane * 4);
        ushort4 v3 = *(const ushort4*)(h + (size_t)q3.x * 256 + lane * 4);
        A1_STEP(q0, v0) A1_STEP(q1, v1) A1_STEP(q2, v2) A1_STEP(q3, v3)
    }
    for (; e < e1; ++e) {
        int2 q = er[e];
        ushort4 v = *(const ushort4*)(h + (size_t)q.x * 256 + lane * 4);
        A1_STEP(q, v)
    }
#undef A1_STEP
    float dn = dinv[n];
    float s2 = dn * dn;
    ushort4 hv = *(const ushort4*)(h + (size_t)n * 256 + lane * 4);
    float4 bb = *(const float4*)(b1 + lane * 4);
    ushort4 r;
    r.x = f2bf(fmaxf(fmaf(acc.x, dn, fmaf(bf2f(hv.x), s2, bb.x)), 0.f));
    r.y = f2bf(fmaxf(fmaf(acc.y, dn, fmaf(bf2f(hv.y), s2, bb.y)), 0.f));
    r.z = f2bf(fmaxf(fmaf(acc.z, dn, fmaf(bf2f(hv.z), s2, bb.z)), 0.f));
    r.w = f2bf(fmaxf(fmaf(acc.w, dn, fmaf(bf2f(hv.w), s2, bb.w)), 0.f));
    *(ushort4*)(out + (size_t)n * 256 + lane * 4) = r;
}

// ---------------- layer-2 aggregation + bias + log_softmax (f32 h2) ----------------
__global__ __launch_bounds__(256) void k_agg2(const float* __restrict__ h,
                                              const int* __restrict__ rowstart,
                                              const int2* __restrict__ er,
                                              const float* __restrict__ dinv,
                                              const float* __restrict__ b2,
                                              float* __restrict__ out) {
    int wave = threadIdx.x >> 6;
    int lane = threadIdx.x & 63;
    int n = blockIdx.x * 4 + wave;
    if (n >= NODES) return;
    float acc = 0.f;
    int e0 = rowstart[n], e1 = rowstart[n + 1];
    int e = e0;
    for (; e + 4 <= e1; e += 4) {
        int2 q0 = er[e], q1 = er[e + 1], q2 = er[e + 2], q3 = er[e + 3];
        float v0 = h[(size_t)q0.x * 64 + lane];
        float v1 = h[(size_t)q1.x * 64 + lane];
        float v2 = h[(size_t)q2.x * 64 + lane];
        float v3 = h[(size_t)q3.x * 64 + lane];
        acc = fmaf(__int_as_float(q0.y), v0, acc);
        acc = fmaf(__int_as_float(q1.y), v1, acc);
        acc = fmaf(__int_as_float(q2.y), v2, acc);
        acc = fmaf(__int_as_float(q3.y), v3, acc);
    }
    for (; e < e1; ++e) {
        int2 q = er[e];
        acc = fmaf(__int_as_float(q.y), h[(size_t)q.x * 64 + lane], acc);
    }
    float dn = dinv[n];
    float r = fmaf(acc, dn, fmaf(h[(size_t)n * 64 + lane], dn * dn, b2[lane]));
    float m = r;
#pragma unroll
    for (int off = 32; off; off >>= 1) m = fmaxf(m, __shfl_xor(m, off));
    float ex = __expf(r - m);
    float ssum = ex;
#pragma unroll
    for (int off = 32; off; off >>= 1) ssum += __shfl_xor(ssum, off);
    out[(size_t)n * 64 + lane] = r - m - __logf(ssum);
}

// ---------------- launch ----------------

extern "C" void kernel_launch(void* const* d_in, const int* in_sizes, int n_in,
                              void* d_out, int out_size, void* d_ws, size_t ws_size,
                              hipStream_t stream) {
    const float* x  = (const float*)d_in[0];
    const float* W1 = (const float*)d_in[1];
    const float* b1 = (const float*)d_in[2];
    const float* W2 = (const float*)d_in[3];
    const float* b2 = (const float*)d_in[4];
    const int*   ei = (const int*)d_in[5];
    int E = in_sizes[5] / 2;
    const int* src = ei;
    const int* dst = ei + E;
    float* out = (float*)d_out;

    char* wsp = (char*)d_ws;
    auto alloc = [&](size_t bytes) {
        char* p = wsp;
        wsp += (bytes + 255) & ~(size_t)255;
        return p;
    };
    int*    degcnt   = (int*)alloc((size_t)NODES * 4);
    float*  dinv     = (float*)alloc((size_t)NODES * 4);
    int*    rowstart = (int*)alloc((size_t)(NODES + 1) * 4);
    int*    cursor   = (int*)alloc((size_t)NODES * 4);
    int2*   erec     = (int2*)alloc((size_t)E * 8);
    ushort* w1t      = (ushort*)alloc((size_t)256 * 512 * 2);   // W1^T bf16 [256][512]
    ushort* w2t      = (ushort*)alloc((size_t)64 * 256 * 2);    // W2^T bf16 [64][256]
    ushort* h1b      = (ushort*)alloc((size_t)NODES * 256 * 2); // bf16 h1
    ushort* h1ab     = (ushort*)alloc((size_t)NODES * 256 * 2); // bf16 relu(agg1)
    float*  h2       = (float*)alloc((size_t)NODES * 64 * 4);   // f32 h2

    hipMemsetAsync(degcnt, 0, (size_t)NODES * 4, stream);
    hipMemsetAsync(cursor, 0, (size_t)NODES * 4, stream);

    k_count<<<(E + 255) / 256, 256, 0, stream>>>(dst, E, degcnt);
    k_scan<<<1, 1024, 0, stream>>>(degcnt, rowstart, dinv, NODES);
    k_scatter<<<(E + 255) / 256, 256, 0, stream>>>(src, dst, E, rowstart, cursor, dinv, erec);

    // weight casts (tiny)
    k_castT<<<(512 * 256 + 255) / 256, 256, 0, stream>>>(W1, w1t, 512, 256);
    k_castT<<<(256 * 64 + 255) / 256, 256, 0, stream>>>(W2, w2t, 256, 64);

    // layer 1: h1 = x @ W1  (A=f32 x, cast in staging) -> bf16
    k_gemm_bf16<128, 2, true, true><<<dim3((NODES + 127) / 128, 256 / 128), 256, 0, stream>>>(
        x, nullptr, w1t, nullptr, h1b, NODES, 256, 512);
    k_agg1<<<(NODES + 3) / 4, 256, 0, stream>>>(h1b, rowstart, erec, dinv, b1, h1ab);

    // layer 2: h2 = h1a @ W2 -> f32
    k_gemm_bf16<64, 1, false, false><<<dim3((NODES + 127) / 128, 1), 256, 0, stream>>>(
        nullptr, h1ab, w2t, h2, nullptr, NODES, 64, 256);
    k_agg2<<<(NODES + 3) / 4, 256, 0, stream>>>(h2, rowstart, erec, dinv, b2, out);
}

// Round 4
// 426.178 us; speedup vs baseline: 1.9522x; 1.2550x over previous
//
#include <hip/hip_runtime.h>

#define NODES 50000
#define NB ((NODES + 255) / 256)   // 196 scan blocks

typedef __attribute__((ext_vector_type(8))) short short8;
typedef __attribute__((ext_vector_type(4))) float f32x4;

__device__ __forceinline__ ushort f2bf(float f) {
    uint u = __float_as_uint(f);
    uint r = (u + 0x7fffu + ((u >> 16) & 1u)) >> 16;
    return (ushort)r;
}
__device__ __forceinline__ float bf2f(ushort u) {
    return __uint_as_float(((uint)u) << 16);
}

// ---------------- degree / CSR build ----------------

__global__ void k_count(const int* __restrict__ dst, int E, int* __restrict__ degcnt) {
    int e = blockIdx.x * blockDim.x + threadIdx.x;
    if (e < E) atomicAdd(&degcnt[dst[e]], 1);
}

// phase 1: per-block sum of 256 counts
__global__ void k_bsum(const int* __restrict__ cnt, int* __restrict__ bsum) {
    __shared__ int s[256];
    int t = threadIdx.x;
    int i = blockIdx.x * 256 + t;
    s[t] = (i < NODES) ? cnt[i] : 0;
    __syncthreads();
    for (int off = 128; off; off >>= 1) {
        if (t < off) s[t] += s[t + off];
        __syncthreads();
    }
    if (t == 0) bsum[blockIdx.x] = s[0];
}

// phase 2: one block scans the block sums (nb <= 256) -> exclusive offsets
__global__ void k_bscan(const int* __restrict__ bsum, int* __restrict__ boff, int nb) {
    __shared__ int s[256];
    int t = threadIdx.x;
    s[t] = (t < nb) ? bsum[t] : 0;
    __syncthreads();
    for (int off = 1; off < 256; off <<= 1) {
        int v = (t >= off) ? s[t - off] : 0;
        __syncthreads();
        s[t] += v;
        __syncthreads();
    }
    if (t < nb) boff[t] = (t == 0) ? 0 : s[t - 1];
}

// phase 3: per-block local exclusive scan + block offset; fused dinv
__global__ void k_scan3(const int* __restrict__ cnt, const int* __restrict__ boff,
                        int* __restrict__ rowstart, float* __restrict__ dinv) {
    __shared__ int s[256];
    int t = threadIdx.x;
    int i = blockIdx.x * 256 + t;
    int v = (i < NODES) ? cnt[i] : 0;
    s[t] = v;
    __syncthreads();
    for (int off = 1; off < 256; off <<= 1) {
        int u = (t >= off) ? s[t - off] : 0;
        __syncthreads();
        s[t] += u;
        __syncthreads();
    }
    if (i < NODES) {
        int excl = (t == 0) ? 0 : s[t - 1];
        rowstart[i] = boff[blockIdx.x] + excl;
        dinv[i] = rsqrtf(1.0f + (float)v);
        if (i == NODES - 1) rowstart[NODES] = boff[blockIdx.x] + s[t];
    }
}

// edge record: {src, bits(dinv[src])} -> one broadcast 8B load per edge later
__global__ void k_scatter(const int* __restrict__ src, const int* __restrict__ dst, int E,
                          const int* __restrict__ rowstart, int* __restrict__ cursor,
                          const float* __restrict__ dinv, int2* __restrict__ erec) {
    int e = blockIdx.x * blockDim.x + threadIdx.x;
    if (e < E) {
        int d = dst[e];
        int s = src[e];
        int p = atomicAdd(&cursor[d], 1);
        erec[rowstart[d] + p] = make_int2(s, __float_as_int(dinv[s]));
    }
}

// ---------------- casts ----------------

// in [R][C] f32 -> out [C][R] bf16 (transpose cast; weights only)
__global__ void k_castT(const float* __restrict__ in, ushort* __restrict__ out, int R, int C) {
    int i = blockIdx.x * blockDim.x + threadIdx.x;
    if (i >= R * C) return;
    int r = i / C, c = i % C;
    out[(size_t)c * R + r] = f2bf(in[i]);
}

// ---------------- bf16 MFMA GEMM: C[M,N] = A[M,K] @ Bt[N,K]^T ----------------
// BM=128; 256 threads = 4 waves. A either f32 (cast during staging) or bf16.
template <int BN, int WN, bool A_F32, bool OUTBF>
__global__ __launch_bounds__(256) void k_gemm_bf16(const float* __restrict__ Af,
                                                   const ushort* __restrict__ Ab,
                                                   const ushort* __restrict__ Bt,
                                                   float* __restrict__ C,
                                                   ushort* __restrict__ Cb,
                                                   int M, int N, int K) {
    constexpr int WM = 4 / WN;
    constexpr int WTM = 128 / WM;
    constexpr int WTN = BN / WN;
    constexpr int MT = WTM / 16;
    constexpr int NT = WTN / 16;
    constexpr int SA = 48;  // padded LDS row stride (elems)
    __shared__ ushort As[128 * SA];
    __shared__ ushort Bs[BN * SA];

    int t = threadIdx.x;
    int w = t >> 6, l = t & 63;
    int wm = w % WM, wn = w / WM;
    int bm = blockIdx.x * 128, bn = blockIdx.y * BN;
    int lr = l & 15, lk = (l >> 4) * 8;

    f32x4 acc[MT][NT] = {};
    const int ACH = 128 * 4;
    const int BCH = BN * 4;

    for (int k0 = 0; k0 < K; k0 += 32) {
        for (int c = t; c < ACH + BCH; c += 256) {
            if (c < ACH) {
                int row = c >> 2, seg = c & 3;
                int gr = bm + row;
                if (A_F32) {
                    ushort r[8] = {0, 0, 0, 0, 0, 0, 0, 0};
                    if (gr < M) {
                        float4 a = *(const float4*)(Af + (size_t)gr * K + k0 + seg * 8);
                        float4 b = *(const float4*)(Af + (size_t)gr * K + k0 + seg * 8 + 4);
                        r[0] = f2bf(a.x); r[1] = f2bf(a.y); r[2] = f2bf(a.z); r[3] = f2bf(a.w);
                        r[4] = f2bf(b.x); r[5] = f2bf(b.y); r[6] = f2bf(b.z); r[7] = f2bf(b.w);
                    }
                    *(int4*)(&As[row * SA + seg * 8]) = *(int4*)r;
                } else {
                    int4 v = make_int4(0, 0, 0, 0);
                    if (gr < M) v = *(const int4*)(Ab + (size_t)gr * K + k0 + seg * 8);
                    *(int4*)(&As[row * SA + seg * 8]) = v;
                }
            } else {
                int cc = c - ACH;
                int row = cc >> 2, seg = cc & 3;
                int4 v = *(const int4*)(Bt + (size_t)(bn + row) * K + k0 + seg * 8);
                *(int4*)(&Bs[row * SA + seg * 8]) = v;
            }
        }
        __syncthreads();
        short8 af[MT], bfr[NT];
#pragma unroll
        for (int mt = 0; mt < MT; ++mt)
            af[mt] = *(const short8*)(&As[(wm * WTM + mt * 16 + lr) * SA + lk]);
#pragma unroll
        for (int nt = 0; nt < NT; ++nt)
            bfr[nt] = *(const short8*)(&Bs[(wn * WTN + nt * 16 + lr) * SA + lk]);
#pragma unroll
        for (int mt = 0; mt < MT; ++mt)
#pragma unroll
            for (int nt = 0; nt < NT; ++nt)
                acc[mt][nt] = __builtin_amdgcn_mfma_f32_16x16x32_bf16(af[mt], bfr[nt], acc[mt][nt], 0, 0, 0);
        __syncthreads();
    }

#pragma unroll
    for (int mt = 0; mt < MT; ++mt)
#pragma unroll
        for (int nt = 0; nt < NT; ++nt)
#pragma unroll
            for (int i = 0; i < 4; ++i) {
                int row = bm + wm * WTM + mt * 16 + (l >> 4) * 4 + i;
                int col = bn + wn * WTN + nt * 16 + lr;
                if (row < M) {
                    float v = acc[mt][nt][i];
                    if (OUTBF) Cb[(size_t)row * N + col] = f2bf(v);
                    else       C[(size_t)row * N + col] = v;
                }
            }
}

// ---------------- layer-1 aggregation + bias + relu (bf16 in / bf16 out) ----------------
// one wave per node; lane l owns dims 4l..4l+3; edge loop unrolled x4 for MLP
__global__ __launch_bounds__(256) void k_agg1(const ushort* __restrict__ h,
                                              const int* __restrict__ rowstart,
                                              const int2* __restrict__ er,
                                              const float* __restrict__ dinv,
                                              const float* __restrict__ b1,
                                              ushort* __restrict__ out) {
    int wave = threadIdx.x >> 6;
    int lane = threadIdx.x & 63;
    int n = blockIdx.x * 4 + wave;
    if (n >= NODES) return;
    float4 acc = make_float4(0.f, 0.f, 0.f, 0.f);
    int e0 = rowstart[n], e1 = rowstart[n + 1];
    int e = e0;
#define A1_STEP(q, v)                                             \
    {                                                             \
        float w = __int_as_float((q).y);                          \
        acc.x = fmaf(w, bf2f((v).x), acc.x);                      \
        acc.y = fmaf(w, bf2f((v).y), acc.y);                      \
        acc.z = fmaf(w, bf2f((v).z), acc.z);                      \
        acc.w = fmaf(w, bf2f((v).w), acc.w);                      \
    }
    for (; e + 4 <= e1; e += 4) {
        int2 q0 = er[e], q1 = er[e + 1], q2 = er[e + 2], q3 = er[e + 3];
        ushort4 v0 = *(const ushort4*)(h + (size_t)q0.x * 256 + lane * 4);
        ushort4 v1 = *(const ushort4*)(h + (size_t)q1.x * 256 + lane * 4);
        ushort4 v2 = *(const ushort4*)(h + (size_t)q2.x * 256 + lane * 4);
        ushort4 v3 = *(const ushort4*)(h + (size_t)q3.x * 256 + lane * 4);
        A1_STEP(q0, v0) A1_STEP(q1, v1) A1_STEP(q2, v2) A1_STEP(q3, v3)
    }
    for (; e < e1; ++e) {
        int2 q = er[e];
        ushort4 v = *(const ushort4*)(h + (size_t)q.x * 256 + lane * 4);
        A1_STEP(q, v)
    }
#undef A1_STEP
    float dn = dinv[n];
    float s2 = dn * dn;
    ushort4 hv = *(const ushort4*)(h + (size_t)n * 256 + lane * 4);
    float4 bb = *(const float4*)(b1 + lane * 4);
    ushort4 r;
    r.x = f2bf(fmaxf(fmaf(acc.x, dn, fmaf(bf2f(hv.x), s2, bb.x)), 0.f));
    r.y = f2bf(fmaxf(fmaf(acc.y, dn, fmaf(bf2f(hv.y), s2, bb.y)), 0.f));
    r.z = f2bf(fmaxf(fmaf(acc.z, dn, fmaf(bf2f(hv.z), s2, bb.z)), 0.f));
    r.w = f2bf(fmaxf(fmaf(acc.w, dn, fmaf(bf2f(hv.w), s2, bb.w)), 0.f));
    *(ushort4*)(out + (size_t)n * 256 + lane * 4) = r;
}

// ---------------- layer-2 aggregation + bias + log_softmax (f32 h2) ----------------
__global__ __launch_bounds__(256) void k_agg2(const float* __restrict__ h,
                                              const int* __restrict__ rowstart,
                                              const int2* __restrict__ er,
                                              const float* __restrict__ dinv,
                                              const float* __restrict__ b2,
                                              float* __restrict__ out) {
    int wave = threadIdx.x >> 6;
    int lane = threadIdx.x & 63;
    int n = blockIdx.x * 4 + wave;
    if (n >= NODES) return;
    float acc = 0.f;
    int e0 = rowstart[n], e1 = rowstart[n + 1];
    int e = e0;
    for (; e + 4 <= e1; e += 4) {
        int2 q0 = er[e], q1 = er[e + 1], q2 = er[e + 2], q3 = er[e + 3];
        float v0 = h[(size_t)q0.x * 64 + lane];
        float v1 = h[(size_t)q1.x * 64 + lane];
        float v2 = h[(size_t)q2.x * 64 + lane];
        float v3 = h[(size_t)q3.x * 64 + lane];
        acc = fmaf(__int_as_float(q0.y), v0, acc);
        acc = fmaf(__int_as_float(q1.y), v1, acc);
        acc = fmaf(__int_as_float(q2.y), v2, acc);
        acc = fmaf(__int_as_float(q3.y), v3, acc);
    }
    for (; e < e1; ++e) {
        int2 q = er[e];
        acc = fmaf(__int_as_float(q.y), h[(size_t)q.x * 64 + lane], acc);
    }
    float dn = dinv[n];
    float r = fmaf(acc, dn, fmaf(h[(size_t)n * 64 + lane], dn * dn, b2[lane]));
    float m = r;
#pragma unroll
    for (int off = 32; off; off >>= 1) m = fmaxf(m, __shfl_xor(m, off));
    float ex = __expf(r - m);
    float ssum = ex;
#pragma unroll
    for (int off = 32; off; off >>= 1) ssum += __shfl_xor(ssum, off);
    out[(size_t)n * 64 + lane] = r - m - __logf(ssum);
}

// ---------------- launch ----------------

extern "C" void kernel_launch(void* const* d_in, const int* in_sizes, int n_in,
                              void* d_out, int out_size, void* d_ws, size_t ws_size,
                              hipStream_t stream) {
    const float* x  = (const float*)d_in[0];
    const float* W1 = (const float*)d_in[1];
    const float* b1 = (const float*)d_in[2];
    const float* W2 = (const float*)d_in[3];
    const float* b2 = (const float*)d_in[4];
    const int*   ei = (const int*)d_in[5];
    int E = in_sizes[5] / 2;
    const int* src = ei;
    const int* dst = ei + E;
    float* out = (float*)d_out;

    char* wsp = (char*)d_ws;
    auto alloc = [&](size_t bytes) {
        char* p = wsp;
        wsp += (bytes + 255) & ~(size_t)255;
        return p;
    };
    int*    degcnt   = (int*)alloc((size_t)NODES * 4);
    float*  dinv     = (float*)alloc((size_t)NODES * 4);
    int*    rowstart = (int*)alloc((size_t)(NODES + 1) * 4);
    int*    cursor   = (int*)alloc((size_t)NODES * 4);
    int*    bsum     = (int*)alloc((size_t)NB * 4);
    int*    boff     = (int*)alloc((size_t)NB * 4);
    int2*   erec     = (int2*)alloc((size_t)E * 8);
    ushort* w1t      = (ushort*)alloc((size_t)256 * 512 * 2);   // W1^T bf16 [256][512]
    ushort* w2t      = (ushort*)alloc((size_t)64 * 256 * 2);    // W2^T bf16 [64][256]
    ushort* h1b      = (ushort*)alloc((size_t)NODES * 256 * 2); // bf16 h1
    ushort* h1ab     = (ushort*)alloc((size_t)NODES * 256 * 2); // bf16 relu(agg1)
    float*  h2       = (float*)alloc((size_t)NODES * 64 * 4);   // f32 h2

    hipMemsetAsync(degcnt, 0, (size_t)NODES * 4, stream);
    hipMemsetAsync(cursor, 0, (size_t)NODES * 4, stream);

    k_count<<<(E + 255) / 256, 256, 0, stream>>>(dst, E, degcnt);
    k_bsum<<<NB, 256, 0, stream>>>(degcnt, bsum);
    k_bscan<<<1, 256, 0, stream>>>(bsum, boff, NB);
    k_scan3<<<NB, 256, 0, stream>>>(degcnt, boff, rowstart, dinv);
    k_scatter<<<(E + 255) / 256, 256, 0, stream>>>(src, dst, E, rowstart, cursor, dinv, erec);

    // weight casts (tiny)
    k_castT<<<(512 * 256 + 255) / 256, 256, 0, stream>>>(W1, w1t, 512, 256);
    k_castT<<<(256 * 64 + 255) / 256, 256, 0, stream>>>(W2, w2t, 256, 64);

    // layer 1: h1 = x @ W1  (A=f32 x, cast in staging) -> bf16
    k_gemm_bf16<128, 2, true, true><<<dim3((NODES + 127) / 128, 256 / 128), 256, 0, stream>>>(
        x, nullptr, w1t, nullptr, h1b, NODES, 256, 512);
    k_agg1<<<(NODES + 3) / 4, 256, 0, stream>>>(h1b, rowstart, erec, dinv, b1, h1ab);

    // layer 2: h2 = h1a @ W2 -> f32
    k_gemm_bf16<64, 1, false, false><<<dim3((NODES + 127) / 128, 1), 256, 0, stream>>>(
        nullptr, h1ab, w2t, h2, nullptr, NODES, 64, 256);
    k_agg2<<<(NODES + 3) / 4, 256, 0, stream>>>(h2, rowstart, erec, dinv, b2, out);
}